// Round 5
// baseline (324.890 us; speedup 1.0000x reference)
//
#include <hip/hip_runtime.h>
#include <hip/hip_bf16.h>
#include <math.h>

#define NN 262144
#define NCC 65536

typedef __bf16 bf16x8 __attribute__((ext_vector_type(8)));
typedef float f32x4 __attribute__((ext_vector_type(4)));

// ---------- setup: blocks 0..47 precompute Mt; blocks 48..175 zero flags ----------
__global__ __launch_bounds__(256) void k_setup(const float* __restrict__ w_orig,
                                               const float* __restrict__ w_prop,
                                               const float* __restrict__ w_ctx,
                                               const float* __restrict__ W_fuse,
                                               __bf16* __restrict__ Mt,
                                               unsigned char* __restrict__ flags) {
    __shared__ float Wl[64 * 65];
    __shared__ float wl[64 * 65];
    int b = blockIdx.x;
    int t = threadIdx.x;
    if (b >= 48) {   // zero 2*NN flag bytes: 128 blocks * 256 threads * 16B
        ((uint4*)flags)[(b - 48) * 256 + t] = make_uint4(0u, 0u, 0u, 0u);
        return;
    }
    int seg = b >> 4, rem = b & 15;
    int ot = rem >> 2, mt = rem & 3;
    const float* wseg = seg == 0 ? w_orig : (seg == 1 ? w_prop : w_ctx);
    int to = (t & 15) * 4, tm = (t >> 4) * 4;
    float acc[4][4] = {};
    for (int kc = 0; kc < 4; ++kc) {
        __syncthreads();
        for (int i = 0; i < 16; ++i) {
            int f = i * 256 + t;
            int row = f >> 6, col = f & 63;
            Wl[row * 65 + col] = W_fuse[(size_t)(ot * 64 + row) * 768 + seg * 256 + kc * 64 + col];
            wl[row * 65 + col] = wseg[(size_t)(mt * 64 + row) * 256 + kc * 64 + col];
        }
        __syncthreads();
        for (int k = 0; k < 64; ++k) {
            float wo[4], wm2[4];
#pragma unroll
            for (int i = 0; i < 4; ++i) wo[i] = Wl[(to + i) * 65 + k];
#pragma unroll
            for (int j = 0; j < 4; ++j) wm2[j] = wl[(tm + j) * 65 + k];
#pragma unroll
            for (int i = 0; i < 4; ++i)
#pragma unroll
                for (int j = 0; j < 4; ++j) acc[i][j] += wo[i] * wm2[j];
        }
    }
    for (int i = 0; i < 4; ++i)
        for (int j = 0; j < 4; ++j) {
            int o = ot * 64 + to + i;
            int g = seg * 256 + mt * 64 + tm + j;
            Mt[(size_t)o * 768 + g] = (__bf16)acc[i][j];
        }
}

__global__ void k_setflags(const int* __restrict__ idxp, const int* __restrict__ idxc,
                           unsigned char* fp, unsigned char* fc) {
    int j = blockIdx.x * blockDim.x + threadIdx.x;
    if (j < NCC) { fp[idxp[j]] = 1; fc[idxc[j]] = 1; }
}

__device__ inline bf16x8 cvt8(f32x4 a, f32x4 b) {
    bf16x8 w;
    w[0] = (__bf16)a[0]; w[1] = (__bf16)a[1]; w[2] = (__bf16)a[2]; w[3] = (__bf16)a[3];
    w[4] = (__bf16)b[0]; w[5] = (__bf16)b[1]; w[6] = (__bf16)b[2]; w[7] = (__bf16)b[3];
    return w;
}

// ---------- gathered GEMM, 64x256 tile, 8 waves, 2-deep A prefetch, LDS-transposed epilogue ----------
__global__ __launch_bounds__(512, 4) void k_gemm(const float* __restrict__ hp,
                                                 const float* __restrict__ hc,
                                                 const float* __restrict__ horig,
                                                 const __bf16* __restrict__ Mt,
                                                 const float* __restrict__ bfuse,
                                                 const float* __restrict__ bias,
                                                 const int* __restrict__ idxp,
                                                 const int* __restrict__ idxc,
                                                 float* __restrict__ out0,
                                                 float* __restrict__ out1) {
    __shared__ char smem[40960];
    __bf16* Al = (__bf16*)smem;            // 8 KB, swizzled
    __bf16* Bl = (__bf16*)(smem + 8192);   // 32 KB, swizzled
    int t = threadIdx.x;
    int jbase = blockIdx.x * 64;
    int lane = t & 63, wid = t >> 6;
    int wm = wid >> 2, wn = wid & 3;
    int l15 = lane & 15, lq = lane >> 4;

    // A staging: thread -> (row ar, 8-f32 slot aslot)
    int ar = t >> 3, aslot = t & 7;
    int jr = jbase + ar;
    const float* rowp0 = horig + (size_t)jr * 256 + aslot * 8;
    const float* rowp1 = hp + (size_t)idxp[jr] * 256 + aslot * 8;
    const float* rowp2 = hc + (size_t)idxc[jr] * 256 + aslot * 8;

    // B staging: thread -> (row bo, 32-elem half bkp)
    int bo = t >> 1, bkp = t & 1;
    const __bf16* bsrc = Mt + (size_t)bo * 768 + bkp * 32;

    f32x4 a0[2], a1[2];
    bf16x8 vb[4];
    {   // prologue: A chunks 0,1; B chunk 0
        a0[0] = *(const f32x4*)(rowp0);       a1[0] = *(const f32x4*)(rowp0 + 4);
        a0[1] = *(const f32x4*)(rowp0 + 64);  a1[1] = *(const f32x4*)(rowp0 + 68);
#pragma unroll
        for (int i = 0; i < 4; ++i) vb[i] = *(const bf16x8*)(bsrc + i * 8);
    }

    f32x4 acc[2][4] = {};

#pragma unroll
    for (int c = 0; c < 12; ++c) {
        int s = c & 1;
        __syncthreads();   // previous compute done; safe to overwrite LDS
        *(bf16x8*)&Al[ar * 64 + ((aslot ^ (ar & 7)) << 3)] = cvt8(a0[s], a1[s]);
#pragma unroll
        for (int i = 0; i < 4; ++i) {
            int slot = bkp * 4 + i;
            *(bf16x8*)&Bl[bo * 64 + ((slot ^ (bo & 7)) << 3)] = vb[i];
        }
        // prefetch: B for c+1 (L2), A for c+2 (HBM gather, 2-deep)
        if (c < 11) {
#pragma unroll
            for (int i = 0; i < 4; ++i) vb[i] = *(const bf16x8*)(bsrc + (c + 1) * 64 + i * 8);
        }
        if (c < 10) {
            int cn = c + 2;
            int seg = cn >> 2, ko = (cn & 3) * 64;
            const float* sp = (seg == 0 ? rowp0 : (seg == 1 ? rowp1 : rowp2)) + ko;
            a0[s] = *(const f32x4*)(sp);
            a1[s] = *(const f32x4*)(sp + 4);
        }
        __syncthreads();
        // compute chunk c
#pragma unroll
        for (int ks = 0; ks < 2; ++ks) {
            bf16x8 af[2], bfr[4];
            int kslot = ks * 4 + lq;
#pragma unroll
            for (int mi = 0; mi < 2; ++mi) {
                int r = wm * 32 + mi * 16 + l15;
                af[mi] = *(const bf16x8*)&Al[r * 64 + ((kslot ^ (r & 7)) << 3)];
            }
#pragma unroll
            for (int ni = 0; ni < 4; ++ni) {
                int o = wn * 64 + ni * 16 + l15;
                bfr[ni] = *(const bf16x8*)&Bl[o * 64 + ((kslot ^ (o & 7)) << 3)];
            }
#pragma unroll
            for (int mi = 0; mi < 2; ++mi)
#pragma unroll
                for (int ni = 0; ni < 4; ++ni)
                    acc[mi][ni] = __builtin_amdgcn_mfma_f32_16x16x32_bf16(af[mi], bfr[ni], acc[mi][ni], 0, 0, 0);
        }
    }

    // ---- epilogue: per-wave LDS transpose -> f32x4 row-contiguous stores ----
    float bfv[4], biv[4];
#pragma unroll
    for (int ni = 0; ni < 4; ++ni) {
        int o = wn * 64 + ni * 16 + l15;
        bfv[ni] = bfuse[o];
        biv[ni] = bias[o];
    }
    __syncthreads();   // all LDS reads of main loop done; reuse Bl region as scratch
    float* scr = (float*)(smem + 8192 + wid * 4096);   // per-wave 16x64 f32
#pragma unroll
    for (int mi = 0; mi < 2; ++mi) {
#pragma unroll
        for (int ni = 0; ni < 4; ++ni)
#pragma unroll
            for (int rr = 0; rr < 4; ++rr) {
                float v = tanhf(acc[mi][ni][rr] + bfv[ni]) + biv[ni];
                scr[(lq * 4 + rr) * 64 + ni * 16 + l15] = v;
            }
        // intra-wave ds ordering guarantees the writes above are visible to our own reads
#pragma unroll
        for (int rnd = 0; rnd < 4; ++rnd) {
            int rr2 = rnd * 4 + lq;
            int j = jbase + wm * 32 + mi * 16 + rr2;
            int gp = idxp[j], gc = idxc[j];
            f32x4 v = *(const f32x4*)&scr[rr2 * 64 + l15 * 4];
            *(f32x4*)(out0 + (size_t)gp * 256 + wn * 64 + l15 * 4) = v;
            *(f32x4*)(out1 + (size_t)gc * 256 + wn * 64 + l15 * 4) = v;
        }
    }
}

// ---------- masked copy: explicit 8-deep batched phases (flags -> loads -> stores) ----------
__global__ __launch_bounds__(256) void k_copy(const float* __restrict__ hp,
                                              const float* __restrict__ hc,
                                              const unsigned char* __restrict__ fp,
                                              const unsigned char* __restrict__ fc,
                                              float* __restrict__ out0,
                                              float* __restrict__ out1) {
    int tid = blockIdx.x * 256 + threadIdx.x;       // 1,048,576 threads
    const int stride = 4096 * 256;
#pragma unroll
    for (int g = 0; g < 4; ++g) {
        unsigned char fl[8];
#pragma unroll
        for (int i = 0; i < 8; ++i) {
            int gid = (g * 8 + i) * stride + tid;
            int row = gid >> 6;
            int tbl = row >= NN;
            int r = tbl ? row - NN : row;
            fl[i] = (tbl ? fc : fp)[r];
        }
        f32x4 v[8];
#pragma unroll
        for (int i = 0; i < 8; ++i) {
            int gid = (g * 8 + i) * stride + tid;
            int row = gid >> 6, slot = gid & 63;
            int tbl = row >= NN;
            int r = tbl ? row - NN : row;
            const float* S = tbl ? hc : hp;
            // flagged rows redirect read to row 0 (L1-resident) -> loads stay unconditional
            v[i] = *(const f32x4*)(S + (size_t)(fl[i] ? 0 : r) * 256 + slot * 4);
        }
#pragma unroll
        for (int i = 0; i < 8; ++i) {
            int gid = (g * 8 + i) * stride + tid;
            int row = gid >> 6, slot = gid & 63;
            int tbl = row >= NN;
            int r = tbl ? row - NN : row;
            float* D = tbl ? out1 : out0;
            if (!fl[i]) *(f32x4*)(D + (size_t)r * 256 + slot * 4) = v[i];
        }
    }
}

extern "C" void kernel_launch(void* const* d_in, const int* in_sizes, int n_in,
                              void* d_out, int out_size, void* d_ws, size_t ws_size,
                              hipStream_t stream) {
    const float* hp     = (const float*)d_in[0];
    const float* hc     = (const float*)d_in[1];
    const float* horig  = (const float*)d_in[2];
    const float* w_orig = (const float*)d_in[3];
    const float* w_prop = (const float*)d_in[4];
    const float* w_ctx  = (const float*)d_in[5];
    const float* W_fuse = (const float*)d_in[6];
    const float* bfuse  = (const float*)d_in[7];
    const float* bias   = (const float*)d_in[8];
    const int* idxp     = (const int*)d_in[9];
    const int* idxc     = (const int*)d_in[10];
    float* out0 = (float*)d_out;
    float* out1 = out0 + (size_t)NN * 256;

    char* ws = (char*)d_ws;
    __bf16* Mt = (__bf16*)ws;                              // 256*768*2 = 393216 B
    unsigned char* fp = (unsigned char*)(ws + 393216);     // NN bytes
    unsigned char* fc = fp + NN;                           // NN bytes

    k_setup<<<176, 256, 0, stream>>>(w_orig, w_prop, w_ctx, W_fuse, Mt, fp);
    k_setflags<<<NCC / 256, 256, 0, stream>>>(idxp, idxc, fp, fc);
    k_gemm<<<NCC / 64, 512, 0, stream>>>(hp, hc, horig, Mt, bfuse, bias,
                                         idxp, idxc, out0, out1);
    k_copy<<<4096, 256, 0, stream>>>(hp, hc, fp, fc, out0, out1);
}

// Round 6
// 291.024 us; speedup vs baseline: 1.1164x; 1.1164x over previous
//
#include <hip/hip_runtime.h>
#include <hip/hip_bf16.h>
#include <math.h>

#define NN 262144
#define NCC 65536

typedef __bf16 bf16x8 __attribute__((ext_vector_type(8)));
typedef float f32x4 __attribute__((ext_vector_type(4)));

// ---------- setup: blocks 0..47 precompute Mt; blocks 48..175 zero flags ----------
__global__ __launch_bounds__(256) void k_setup(const float* __restrict__ w_orig,
                                               const float* __restrict__ w_prop,
                                               const float* __restrict__ w_ctx,
                                               const float* __restrict__ W_fuse,
                                               __bf16* __restrict__ Mt,
                                               unsigned char* __restrict__ flags) {
    __shared__ float Wl[64 * 65];
    __shared__ float wl[64 * 65];
    int b = blockIdx.x;
    int t = threadIdx.x;
    if (b >= 48) {   // zero 2*NN flag bytes: 128 blocks * 256 threads * 16B
        ((uint4*)flags)[(b - 48) * 256 + t] = make_uint4(0u, 0u, 0u, 0u);
        return;
    }
    int seg = b >> 4, rem = b & 15;
    int ot = rem >> 2, mt = rem & 3;
    const float* wseg = seg == 0 ? w_orig : (seg == 1 ? w_prop : w_ctx);
    int to = (t & 15) * 4, tm = (t >> 4) * 4;
    float acc[4][4] = {};
    for (int kc = 0; kc < 4; ++kc) {
        __syncthreads();
        for (int i = 0; i < 16; ++i) {
            int f = i * 256 + t;
            int row = f >> 6, col = f & 63;
            Wl[row * 65 + col] = W_fuse[(size_t)(ot * 64 + row) * 768 + seg * 256 + kc * 64 + col];
            wl[row * 65 + col] = wseg[(size_t)(mt * 64 + row) * 256 + kc * 64 + col];
        }
        __syncthreads();
        for (int k = 0; k < 64; ++k) {
            float wo[4], wm2[4];
#pragma unroll
            for (int i = 0; i < 4; ++i) wo[i] = Wl[(to + i) * 65 + k];
#pragma unroll
            for (int j = 0; j < 4; ++j) wm2[j] = wl[(tm + j) * 65 + k];
#pragma unroll
            for (int i = 0; i < 4; ++i)
#pragma unroll
                for (int j = 0; j < 4; ++j) acc[i][j] += wo[i] * wm2[j];
        }
    }
    for (int i = 0; i < 4; ++i)
        for (int j = 0; j < 4; ++j) {
            int o = ot * 64 + to + i;
            int g = seg * 256 + mt * 64 + tm + j;
            Mt[(size_t)o * 768 + g] = (__bf16)acc[i][j];
        }
}

__global__ void k_setflags(const int* __restrict__ idxp, const int* __restrict__ idxc,
                           unsigned char* fp, unsigned char* fc) {
    int j = blockIdx.x * blockDim.x + threadIdx.x;
    if (j < NCC) { fp[idxp[j]] = 1; fc[idxc[j]] = 1; }
}

__device__ inline bf16x8 cvt8(f32x4 a, f32x4 b) {
    bf16x8 w;
    w[0] = (__bf16)a[0]; w[1] = (__bf16)a[1]; w[2] = (__bf16)a[2]; w[3] = (__bf16)a[3];
    w[4] = (__bf16)b[0]; w[5] = (__bf16)b[1]; w[6] = (__bf16)b[2]; w[7] = (__bf16)b[3];
    return w;
}

// ---------- one kernel, two block roles: even = copy slab, odd = gemm tile ----------
__global__ __launch_bounds__(512, 4) void k_main(const float* __restrict__ hp,
                                                 const float* __restrict__ hc,
                                                 const float* __restrict__ horig,
                                                 const __bf16* __restrict__ Mt,
                                                 const float* __restrict__ bfuse,
                                                 const float* __restrict__ bias,
                                                 const int* __restrict__ idxp,
                                                 const int* __restrict__ idxc,
                                                 const unsigned char* __restrict__ fp,
                                                 const unsigned char* __restrict__ fc,
                                                 float* __restrict__ out0,
                                                 float* __restrict__ out1) {
    __shared__ char smem[40960];
    int bid = blockIdx.x >> 1;
    int t = threadIdx.x;

    if (!(blockIdx.x & 1)) {
        // ================= copy role: 512 rows of one table =================
        int tbl = bid >= 512;                   // blocks 0..511 -> hp, 512..1023 -> hc
        const unsigned char* F = tbl ? fc : fp;
        const float* S = tbl ? hc : hp;
        float* D = tbl ? out1 : out0;
        int r0 = (tbl ? bid - 512 : bid) * 512;
#pragma unroll
        for (int g = 0; g < 8; ++g) {
            unsigned char fl[8];
            f32x4 v[8];
#pragma unroll
            for (int i = 0; i < 8; ++i) {
                int gl = (g * 8 + i) * 512 + t;
                fl[i] = F[r0 + (gl >> 6)];
            }
#pragma unroll
            for (int i = 0; i < 8; ++i) {
                int gl = (g * 8 + i) * 512 + t;
                int r = r0 + (gl >> 6), slot = gl & 63;
                // flagged rows redirect read to row 0 (cache-resident) -> load unconditional
                v[i] = *(const f32x4*)(S + (size_t)(fl[i] ? 0 : r) * 256 + slot * 4);
            }
#pragma unroll
            for (int i = 0; i < 8; ++i) {
                int gl = (g * 8 + i) * 512 + t;
                int r = r0 + (gl >> 6), slot = gl & 63;
                if (!fl[i]) *(f32x4*)(D + (size_t)r * 256 + slot * 4) = v[i];   // wave-uniform
            }
        }
        return;
    }

    // ================= gemm role: 64x256 output tile =================
    __bf16* Al = (__bf16*)smem;            // 8 KB, swizzled
    __bf16* Bl = (__bf16*)(smem + 8192);   // 32 KB, swizzled
    int jbase = bid * 64;
    int lane = t & 63, wid = t >> 6;
    int wm = wid >> 2, wn = wid & 3;
    int l15 = lane & 15, lq = lane >> 4;

    // A staging: thread -> (row ar, 8-f32 slot aslot)
    int ar = t >> 3, aslot = t & 7;
    int jr = jbase + ar;
    const float* rowp0 = horig + (size_t)jr * 256 + aslot * 8;
    const float* rowp1 = hp + (size_t)idxp[jr] * 256 + aslot * 8;
    const float* rowp2 = hc + (size_t)idxc[jr] * 256 + aslot * 8;

    // B staging: thread -> (row bo, 32-elem half bkp)
    int bo = t >> 1, bkp = t & 1;
    const __bf16* bsrc = Mt + (size_t)bo * 768 + bkp * 32;

    f32x4 a0[2], a1[2];
    bf16x8 vb[4];
    {   // prologue: A chunks 0,1; B chunk 0
        a0[0] = *(const f32x4*)(rowp0);       a1[0] = *(const f32x4*)(rowp0 + 4);
        a0[1] = *(const f32x4*)(rowp0 + 64);  a1[1] = *(const f32x4*)(rowp0 + 68);
#pragma unroll
        for (int i = 0; i < 4; ++i) vb[i] = *(const bf16x8*)(bsrc + i * 8);
    }

    f32x4 acc[2][4] = {};

#pragma unroll
    for (int c = 0; c < 12; ++c) {
        int s = c & 1;
        __syncthreads();
        *(bf16x8*)&Al[ar * 64 + ((aslot ^ (ar & 7)) << 3)] = cvt8(a0[s], a1[s]);
#pragma unroll
        for (int i = 0; i < 4; ++i) {
            int slot = bkp * 4 + i;
            *(bf16x8*)&Bl[bo * 64 + ((slot ^ (bo & 7)) << 3)] = vb[i];
        }
        if (c < 11) {
#pragma unroll
            for (int i = 0; i < 4; ++i) vb[i] = *(const bf16x8*)(bsrc + (c + 1) * 64 + i * 8);
        }
        if (c < 10) {
            int cn = c + 2;
            int seg = cn >> 2, ko = (cn & 3) * 64;
            const float* sp = (seg == 0 ? rowp0 : (seg == 1 ? rowp1 : rowp2)) + ko;
            a0[s] = *(const f32x4*)(sp);
            a1[s] = *(const f32x4*)(sp + 4);
        }
        __syncthreads();
#pragma unroll
        for (int ks = 0; ks < 2; ++ks) {
            bf16x8 af[2], bfr[4];
            int kslot = ks * 4 + lq;
#pragma unroll
            for (int mi = 0; mi < 2; ++mi) {
                int r = wm * 32 + mi * 16 + l15;
                af[mi] = *(const bf16x8*)&Al[r * 64 + ((kslot ^ (r & 7)) << 3)];
            }
#pragma unroll
            for (int ni = 0; ni < 4; ++ni) {
                int o = wn * 64 + ni * 16 + l15;
                bfr[ni] = *(const bf16x8*)&Bl[o * 64 + ((kslot ^ (o & 7)) << 3)];
            }
#pragma unroll
            for (int mi = 0; mi < 2; ++mi)
#pragma unroll
                for (int ni = 0; ni < 4; ++ni)
                    acc[mi][ni] = __builtin_amdgcn_mfma_f32_16x16x32_bf16(af[mi], bfr[ni], acc[mi][ni], 0, 0, 0);
        }
    }

    // epilogue: per-wave LDS transpose -> f32x4 row-contiguous scattered stores
    float bfv[4], biv[4];
#pragma unroll
    for (int ni = 0; ni < 4; ++ni) {
        int o = wn * 64 + ni * 16 + l15;
        bfv[ni] = bfuse[o];
        biv[ni] = bias[o];
    }
    __syncthreads();
    float* scr = (float*)(smem + 8192 + wid * 4096);   // per-wave 16x64 f32
#pragma unroll
    for (int mi = 0; mi < 2; ++mi) {
#pragma unroll
        for (int ni = 0; ni < 4; ++ni)
#pragma unroll
            for (int rr = 0; rr < 4; ++rr) {
                float v = tanhf(acc[mi][ni][rr] + bfv[ni]) + biv[ni];
                scr[(lq * 4 + rr) * 64 + ni * 16 + l15] = v;
            }
#pragma unroll
        for (int rnd = 0; rnd < 4; ++rnd) {
            int rr2 = rnd * 4 + lq;
            int j = jbase + wm * 32 + mi * 16 + rr2;
            int gp = idxp[j], gc = idxc[j];
            f32x4 v = *(const f32x4*)&scr[rr2 * 64 + l15 * 4];
            *(f32x4*)(out0 + (size_t)gp * 256 + wn * 64 + l15 * 4) = v;
            *(f32x4*)(out1 + (size_t)gc * 256 + wn * 64 + l15 * 4) = v;
        }
    }
}

extern "C" void kernel_launch(void* const* d_in, const int* in_sizes, int n_in,
                              void* d_out, int out_size, void* d_ws, size_t ws_size,
                              hipStream_t stream) {
    const float* hp     = (const float*)d_in[0];
    const float* hc     = (const float*)d_in[1];
    const float* horig  = (const float*)d_in[2];
    const float* w_orig = (const float*)d_in[3];
    const float* w_prop = (const float*)d_in[4];
    const float* w_ctx  = (const float*)d_in[5];
    const float* W_fuse = (const float*)d_in[6];
    const float* bfuse  = (const float*)d_in[7];
    const float* bias   = (const float*)d_in[8];
    const int* idxp     = (const int*)d_in[9];
    const int* idxc     = (const int*)d_in[10];
    float* out0 = (float*)d_out;
    float* out1 = out0 + (size_t)NN * 256;

    char* ws = (char*)d_ws;
    __bf16* Mt = (__bf16*)ws;                              // 256*768*2 = 393216 B
    unsigned char* fp = (unsigned char*)(ws + 393216);     // NN bytes
    unsigned char* fc = fp + NN;                           // NN bytes

    k_setup<<<176, 256, 0, stream>>>(w_orig, w_prop, w_ctx, W_fuse, Mt, fp);
    k_setflags<<<NCC / 256, 256, 0, stream>>>(idxp, idxc, fp, fc);
    k_main<<<2048, 512, 0, stream>>>(hp, hc, horig, Mt, bfuse, bias,
                                     idxp, idxc, fp, fc, out0, out1);
}